// Round 7
// baseline (363.163 us; speedup 1.0000x reference)
//
#include <hip/hip_runtime.h>
#include <math.h>

// DILATE loss: 0.5*mean(softDTW) + 0.5*sum(E*Omega)/(B*N*N) + MSE
// B=64, N=256, K=1, gamma=0.01.
//
// One wave per batch, lane p owns rows 4p+1..4p+4. W=2 COLUMN BLOCKING: at
// step s lane p processes column pair q=s-p (cols 2q+1, 2q+2) forward;
// pair q=190-u-p backward. Steps 320->192. Cross-lane boundary row travels
// via 1-step shfl relay (4 values/step). Static-slot buffers (R6 technique)
// for R loads (8 float4 slots, 4-deep prefetch) and LDS x reads.
// (C,S) forward form: R = C - gamma*ln(S), no log2 on the chain.
// Plus a 1-thread clock-probe kernel (8192 clock64 ticks) whose rocprof
// dur_us reveals the actual shader clock (3.4us @2.4GHz vs 14us @600MHz).
//
// ws: [0, 64*257*64*16 B = 16.8 MB) R column slabs [b][col][p] (col 256 =
//     dummy); then 64*4 doubles partial; then probe sink.

#define BB 64
#define NN 256
#define PP 64
#define NPAIR 128                // column pairs
#define NSTEP (NPAIR + PP - 1)   // 191
#define NSTEPP 192               // padded (multiple of 4)
#define NSLAB 257                // 256 real column slabs + 1 dummy
#define DUMMY 256
#define INF_F 100000000.0f
#define ESC 144.26950408889634f   /* (1/gamma) * log2(e) */
#define LSC 0.006931471805599453f /* gamma * ln(2) */

__device__ __forceinline__ float2 cellCS(float2 a, float2 b, float2 c, float t, float x) {
  // softmin in (C,S) form: R = C - LSC*log2(S); chain carries only C (fmin/fma).
  const float M = fminf(a.x, fminf(b.x, c.x));
  const float S = a.y * exp2f((M - a.x) * ESC) + b.y * exp2f((M - b.x) * ESC) +
                  c.y * exp2f((M - c.x) * ESC);
  const float d = t - x;
  return make_float2(fmaf(d, d, M), S);
}

__device__ __forceinline__ int clampq(int q) {
  return q < 0 ? 0 : (q > NPAIR - 1 ? NPAIR - 1 : q);
}

// ---------------- forward ----------------
#define FWD_BODY(S, XQ)                                                                 \
  {                                                                                     \
    const int q_ = (S)-p;                                                               \
    const bool act_ = (q_ >= 0) & (q_ <= NPAIR - 1);                                    \
    const float xa_ = XQ.x, xb_ = XQ.y;                                                 \
    const float2 c00 = cellCS(ob, nb0, pcs0, t0, xa_);                                  \
    const float2 c01 = cellCS(pcs0, c00, pcs1, t1, xa_);                                \
    const float2 c02 = cellCS(pcs1, c01, pcs2, t2, xa_);                                \
    const float2 c03 = cellCS(pcs2, c02, pcs3, t3, xa_);                                \
    const float2 c10 = cellCS(nb0, nb1, c00, t0, xb_);                                  \
    const float2 c11 = cellCS(c00, c10, c01, t1, xb_);                                  \
    const float2 c12 = cellCS(c01, c11, c02, t2, xb_);                                  \
    const float2 c13 = cellCS(c02, c12, c03, t3, xb_);                                  \
    const int s0_ = act_ ? 2 * q_ : DUMMY;                                              \
    const int s1_ = act_ ? 2 * q_ + 1 : DUMMY;                                          \
    Rb[(size_t)s0_ * PP + p] = make_float4(                                             \
        fmaf(-LSC, log2f(c00.y), c00.x), fmaf(-LSC, log2f(c01.y), c01.x),               \
        fmaf(-LSC, log2f(c02.y), c02.x), fmaf(-LSC, log2f(c03.y), c03.x));              \
    Rb[(size_t)s1_ * PP + p] = make_float4(                                             \
        fmaf(-LSC, log2f(c10.y), c10.x), fmaf(-LSC, log2f(c11.y), c11.x),               \
        fmaf(-LSC, log2f(c12.y), c12.x), fmaf(-LSC, log2f(c13.y), c13.x));              \
    pcs0 = act_ ? c10 : pcs0;                                                           \
    pcs1 = act_ ? c11 : pcs1;                                                           \
    pcs2 = act_ ? c12 : pcs2;                                                           \
    pcs3 = act_ ? c13 : pcs3;                                                           \
    const float eC0_ = act_ ? c03.x : INF_F, eS0_ = act_ ? c03.y : 1.0f;                \
    const float eC1_ = act_ ? c13.x : INF_F, eS1_ = act_ ? c13.y : 1.0f;                \
    const float sC0_ = __shfl_up(eC0_, 1), sS0_ = __shfl_up(eS0_, 1);                   \
    const float sC1_ = __shfl_up(eC1_, 1), sS1_ = __shfl_up(eS1_, 1);                   \
    ob = nb1;                                                                           \
    nb0 = (p == 0) ? make_float2(INF_F, 1.0f) : make_float2(sC0_, sS0_);                \
    nb1 = (p == 0) ? make_float2(INF_F, 1.0f) : make_float2(sC1_, sS1_);                \
    XQ = xs2[clampq((S) + 4 - p)];                                                      \
  }

__global__ __launch_bounds__(64, 1) void sdtw_fwd_kernel(
    const float* __restrict__ input, const float* __restrict__ target,
    float4* __restrict__ Rws, double* __restrict__ partial) {
  const int b = blockIdx.x, p = threadIdx.x;
  __shared__ float2 xs2[NN / 2];
  const float4 xv4 = ((const float4*)(input + b * NN))[p];
  const float4 tv4 = ((const float4*)(target + b * NN))[p];
  ((float4*)xs2)[p] = xv4;
  const float t0 = tv4.x, t1 = tv4.y, t2 = tv4.z, t3 = tv4.w;
  __syncthreads();

  double msel;
  {
    const float d0 = xv4.x - tv4.x, d1 = xv4.y - tv4.y;
    const float d2 = xv4.z - tv4.z, d3 = xv4.w - tv4.w;
    msel = (double)(d0 * d0) + (double)(d1 * d1) + (double)(d2 * d2) + (double)(d3 * d3);
  }

  float4* __restrict__ Rb = Rws + (size_t)b * NSLAB * PP;

  // (C,S) state; boundary R=INF -> (INF,1); R[0][0] = (0,1) on lane 0.
  float2 pcs0 = make_float2(INF_F, 1.0f), pcs1 = pcs0, pcs2 = pcs0, pcs3 = pcs0;
  float2 ob = (p == 0) ? make_float2(0.0f, 1.0f) : make_float2(INF_F, 1.0f);
  float2 nb0 = make_float2(INF_F, 1.0f), nb1 = nb0;
  // static x slots (float2 = x[2q], x[2q+1]); slot k serves steps ≡ k mod 4
  float2 xq0 = xs2[clampq(0 - p)];
  float2 xq1 = xs2[clampq(1 - p)];
  float2 xq2 = xs2[clampq(2 - p)];
  float2 xq3 = xs2[clampq(3 - p)];

  for (int s = 0; s < NSTEPP; s += 4) {  // 192 steps; s=191 inactive for all lanes
    FWD_BODY(s + 0, xq0)
    FWD_BODY(s + 1, xq1)
    FWD_BODY(s + 2, xq2)
    FWD_BODY(s + 3, xq3)
  }
  const float rloc = fmaf(-LSC, log2f(pcs3.y), pcs3.x);  // R[N][N] on lane 63
  const float r_nn = __shfl(rloc, PP - 1);

  for (int off = 32; off > 0; off >>= 1) msel += __shfl_xor(msel, off);
  if (p == 0) {
    partial[b * 4 + 0] = (double)r_nn;
    partial[b * 4 + 1] = msel;
  }
}

// ---------------- backward ----------------
#define BWD_BODY(U, RC0, RC1, XQ)                                                       \
  {                                                                                     \
    const int q_ = NSTEP - 1 - (U)-p;                                                   \
    const bool act_ = (q_ >= 0) & (q_ <= NPAIR - 1);                                    \
    const bool jr1_ = act_ & (q_ < NPAIR - 1);                                          \
    const float xa_ = XQ.x, xb_ = XQ.y, xc_ = xcd;                                      \
    const float4 Rc0_ = RC0, Rc1_ = RC1;                                                \
    float d_;                                                                           \
    d_ = t4 - xb_;                                                                      \
    const float wu13 = (act_ & pbq) ? exp2f(((bRb - Rc1_.w) - d_ * d_) * ESC) : 0.f;    \
    d_ = t3 - xc_;                                                                      \
    const float wl13 = jr1_ ? exp2f(((Rr3 - Rc1_.w) - d_ * d_) * ESC) : 0.f;            \
    d_ = t4 - xc_;                                                                      \
    const float wd13 = (jr1_ & pbq) ? exp2f(((bRc - Rc1_.w) - d_ * d_) * ESC) : 0.f;    \
    const float sd13 = ((p == PP - 1) & ((U) == 0)) ? 1.0f : 0.0f;                      \
    const float e13 = wu13 * bEb + wl13 * Er3 + wd13 * bEc + sd13;                      \
    d_ = t3 - xb_;                                                                      \
    const float wu12 = act_ ? exp2f(((Rc1_.w - Rc1_.z) - d_ * d_) * ESC) : 0.f;         \
    d_ = t2 - xc_;                                                                      \
    const float wl12 = jr1_ ? exp2f(((Rr2 - Rc1_.z) - d_ * d_) * ESC) : 0.f;            \
    d_ = t3 - xc_;                                                                      \
    const float wd12 = jr1_ ? exp2f(((Rr3 - Rc1_.z) - d_ * d_) * ESC) : 0.f;            \
    const float e12 = wu12 * e13 + wl12 * Er2 + wd12 * Er3;                             \
    d_ = t2 - xb_;                                                                      \
    const float wu11 = act_ ? exp2f(((Rc1_.z - Rc1_.y) - d_ * d_) * ESC) : 0.f;         \
    d_ = t1 - xc_;                                                                      \
    const float wl11 = jr1_ ? exp2f(((Rr1 - Rc1_.y) - d_ * d_) * ESC) : 0.f;            \
    d_ = t2 - xc_;                                                                      \
    const float wd11 = jr1_ ? exp2f(((Rr2 - Rc1_.y) - d_ * d_) * ESC) : 0.f;            \
    const float e11 = wu11 * e12 + wl11 * Er1 + wd11 * Er2;                             \
    d_ = t1 - xb_;                                                                      \
    const float wu10 = act_ ? exp2f(((Rc1_.y - Rc1_.x) - d_ * d_) * ESC) : 0.f;         \
    d_ = t0 - xc_;                                                                      \
    const float wl10 = jr1_ ? exp2f(((Rr0 - Rc1_.x) - d_ * d_) * ESC) : 0.f;            \
    d_ = t1 - xc_;                                                                      \
    const float wd10 = jr1_ ? exp2f(((Rr1 - Rc1_.x) - d_ * d_) * ESC) : 0.f;            \
    const float e10 = wu10 * e11 + wl10 * Er0 + wd10 * Er1;                             \
    d_ = t4 - xa_;                                                                      \
    const float wu03 = (act_ & pbq) ? exp2f(((bRa - Rc0_.w) - d_ * d_) * ESC) : 0.f;    \
    d_ = t3 - xb_;                                                                      \
    const float wl03 = act_ ? exp2f(((Rc1_.w - Rc0_.w) - d_ * d_) * ESC) : 0.f;         \
    d_ = t4 - xb_;                                                                      \
    const float wd03 = (act_ & pbq) ? exp2f(((bRb - Rc0_.w) - d_ * d_) * ESC) : 0.f;    \
    const float e03 = wu03 * bEa + wl03 * e13 + wd03 * bEb;                             \
    d_ = t3 - xa_;                                                                      \
    const float wu02 = act_ ? exp2f(((Rc0_.w - Rc0_.z) - d_ * d_) * ESC) : 0.f;         \
    d_ = t2 - xb_;                                                                      \
    const float wl02 = act_ ? exp2f(((Rc1_.z - Rc0_.z) - d_ * d_) * ESC) : 0.f;         \
    d_ = t3 - xb_;                                                                      \
    const float wd02 = act_ ? exp2f(((Rc1_.w - Rc0_.z) - d_ * d_) * ESC) : 0.f;         \
    const float e02 = wu02 * e03 + wl02 * e12 + wd02 * e13;                             \
    d_ = t2 - xa_;                                                                      \
    const float wu01 = act_ ? exp2f(((Rc0_.z - Rc0_.y) - d_ * d_) * ESC) : 0.f;         \
    d_ = t1 - xb_;                                                                      \
    const float wl01 = act_ ? exp2f(((Rc1_.y - Rc0_.y) - d_ * d_) * ESC) : 0.f;         \
    d_ = t2 - xb_;                                                                      \
    const float wd01 = act_ ? exp2f(((Rc1_.z - Rc0_.y) - d_ * d_) * ESC) : 0.f;         \
    const float e01 = wu01 * e02 + wl01 * e11 + wd01 * e12;                             \
    d_ = t1 - xa_;                                                                      \
    const float wu00 = act_ ? exp2f(((Rc0_.y - Rc0_.x) - d_ * d_) * ESC) : 0.f;         \
    d_ = t0 - xb_;                                                                      \
    const float wl00 = act_ ? exp2f(((Rc1_.x - Rc0_.x) - d_ * d_) * ESC) : 0.f;         \
    d_ = t1 - xb_;                                                                      \
    const float wd00 = act_ ? exp2f(((Rc1_.y - Rc0_.x) - d_ * d_) * ESC) : 0.f;         \
    const float e00 = wu00 * e01 + wl00 * e10 + wd00 * e11;                             \
    const float g1_ = (float)(4 * p + 1 - (2 * q_ + 2)); /* i-j for c1 row k=0 */       \
    const float g0_ = g1_ + 1.0f;                        /* i-j for c0 row k=0 */       \
    tsum += (double)(e10 * g1_ * g1_) + (double)(e11 * (g1_ + 1) * (g1_ + 1)) +         \
            (double)(e12 * (g1_ + 2) * (g1_ + 2)) +                                     \
            (double)(e13 * (g1_ + 3) * (g1_ + 3)) + (double)(e00 * g0_ * g0_) +         \
            (double)(e01 * (g0_ + 1) * (g0_ + 1)) +                                     \
            (double)(e02 * (g0_ + 2) * (g0_ + 2)) +                                     \
            (double)(e03 * (g0_ + 3) * (g0_ + 3));                                      \
    Er0 = act_ ? e00 : Er0;                                                             \
    Er1 = act_ ? e01 : Er1;                                                             \
    Er2 = act_ ? e02 : Er2;                                                             \
    Er3 = act_ ? e03 : Er3;                                                             \
    Rr0 = act_ ? Rc0_.x : Rr0;                                                          \
    Rr1 = act_ ? Rc0_.y : Rr1;                                                          \
    Rr2 = act_ ? Rc0_.z : Rr2;                                                          \
    Rr3 = act_ ? Rc0_.w : Rr3;                                                          \
    const float sE0_ = __shfl_down(e00, 1), sE1_ = __shfl_down(e10, 1);                 \
    const float sR0_ = __shfl_down(Rc0_.x, 1), sR1_ = __shfl_down(Rc1_.x, 1);           \
    bEc = bEa;                                                                          \
    bRc = bRa;                                                                          \
    bEa = sE0_;                                                                         \
    bEb = sE1_;                                                                         \
    bRa = sR0_;                                                                         \
    bRb = sR1_;                                                                         \
    xcd = xa_;                                                                          \
    {                                                                                   \
      const int qn_ = clampq(q_ - 4);                                                   \
      RC0 = Rb[(size_t)(2 * qn_) * PP + p];                                             \
      RC1 = Rb[(size_t)(2 * qn_ + 1) * PP + p];                                         \
    }                                                                                   \
    XQ = xs2[clampq(q_ - 4)];                                                           \
  }

__global__ __launch_bounds__(64, 1) void sdtw_bwd_kernel(
    const float* __restrict__ input, const float* __restrict__ target,
    const float4* __restrict__ Rws, double* __restrict__ partial) {
  const int b = blockIdx.x, p = threadIdx.x;
  __shared__ float2 xs2[NN / 2];
  const float4 xv4 = ((const float4*)(input + b * NN))[p];
  const float4 tv4 = ((const float4*)(target + b * NN))[p];
  ((float4*)xs2)[p] = xv4;
  const float t0 = tv4.x, t1 = tv4.y, t2 = tv4.z, t3 = tv4.w;
  const float t4 = __shfl_down(t0, 1);  // t of row 4p+5 (pbq-guarded use)
  __syncthreads();

  const float4* __restrict__ Rb = Rws + (size_t)b * NSLAB * PP;
  // static R slots: body k consumes RBka/RBkb loaded 4 steps earlier
  float4 RB0a = Rb[(size_t)(2 * clampq(NSTEP - 1 - 0 - p)) * PP + p];
  float4 RB0b = Rb[(size_t)(2 * clampq(NSTEP - 1 - 0 - p) + 1) * PP + p];
  float4 RB1a = Rb[(size_t)(2 * clampq(NSTEP - 1 - 1 - p)) * PP + p];
  float4 RB1b = Rb[(size_t)(2 * clampq(NSTEP - 1 - 1 - p) + 1) * PP + p];
  float4 RB2a = Rb[(size_t)(2 * clampq(NSTEP - 1 - 2 - p)) * PP + p];
  float4 RB2b = Rb[(size_t)(2 * clampq(NSTEP - 1 - 2 - p) + 1) * PP + p];
  float4 RB3a = Rb[(size_t)(2 * clampq(NSTEP - 1 - 3 - p)) * PP + p];
  float4 RB3b = Rb[(size_t)(2 * clampq(NSTEP - 1 - 3 - p) + 1) * PP + p];
  float2 xq0 = xs2[clampq(NSTEP - 1 - 0 - p)];
  float2 xq1 = xs2[clampq(NSTEP - 1 - 1 - p)];
  float2 xq2 = xs2[clampq(NSTEP - 1 - 2 - p)];
  float2 xq3 = xs2[clampq(NSTEP - 1 - 3 - p)];
  float xcd = 0.0f;  // x[c1] delayed; first active step has jr1 false -> unused
  float Er0 = 0.f, Er1 = 0.f, Er2 = 0.f, Er3 = 0.f;  // E[rows][2q+3]
  float Rr0 = 0.f, Rr1 = 0.f, Rr2 = 0.f, Rr3 = 0.f;  // R[rows][2q+3]
  float bEa = 0.f, bEb = 0.f, bEc = 0.f;  // E[4p+5][2q+1], [2q+2], [2q+3]
  float bRa = 0.f, bRb = 0.f, bRc = 0.f;  // R[4p+5][...]
  const bool pbq = (p < PP - 1);
  double tsum = 0.0;

  for (int u = 0; u < NSTEPP; u += 4) {  // 192 steps; u=191 inactive for all lanes
    BWD_BODY(u + 0, RB0a, RB0b, xq0)
    BWD_BODY(u + 1, RB1a, RB1b, xq1)
    BWD_BODY(u + 2, RB2a, RB2b, xq2)
    BWD_BODY(u + 3, RB3a, RB3b, xq3)
  }
  for (int off = 32; off > 0; off >>= 1) tsum += __shfl_xor(tsum, off);
  if (p == 0) partial[b * 4 + 2] = tsum;
}

__global__ __launch_bounds__(64) void finalize_kernel(const double* __restrict__ partial,
                                                      float* __restrict__ out) {
  const int t = threadIdx.x;  // one lane per batch
  double sd = partial[t * 4 + 0];
  double ms = partial[t * 4 + 1];
  double ts = partial[t * 4 + 2];
  for (int off = 32; off > 0; off >>= 1) {
    sd += __shfl_xor(sd, off);
    ms += __shfl_xor(ms, off);
    ts += __shfl_xor(ts, off);
  }
  if (t == 0) {
    const double loss_shape = sd / (double)BB;
    const double loss_temporal = ts / ((double)BB * NN * NN);
    const double mse = ms / ((double)BB * NN);
    out[0] = (float)(0.5 * loss_shape + 0.5 * loss_temporal + mse);
  }
}

// Diagnostic: spin for 8192 shader-clock ticks. rocprof dur_us of this
// dispatch reveals the actual clock (3.4us @2.4GHz, ~13.7us @600MHz).
__global__ void clock_probe_kernel(unsigned long long* sink) {
  const unsigned long long s0 = clock64();
  unsigned long long n;
  do {
    n = clock64();
  } while (n - s0 < 8192ULL);
  sink[0] = n;
}

extern "C" void kernel_launch(void* const* d_in, const int* in_sizes, int n_in,
                              void* d_out, int out_size, void* d_ws, size_t ws_size,
                              hipStream_t stream) {
  const float* input = (const float*)d_in[0];
  const float* target = (const float*)d_in[1];
  float4* Rws = (float4*)d_ws;
  double* partial = (double*)((char*)d_ws + (size_t)BB * NSLAB * PP * sizeof(float4));
  unsigned long long* sink = (unsigned long long*)(partial + BB * 4);
  float* out = (float*)d_out;

  sdtw_fwd_kernel<<<BB, PP, 0, stream>>>(input, target, Rws, partial);
  sdtw_bwd_kernel<<<BB, PP, 0, stream>>>(input, target, Rws, partial);
  finalize_kernel<<<1, 64, 0, stream>>>(partial, out);
  clock_probe_kernel<<<1, 1, 0, stream>>>(sink);
}

// Round 10
// 309.142 us; speedup vs baseline: 1.1747x; 1.1747x over previous
//
#include <hip/hip_runtime.h>
#include <math.h>

// DILATE loss: 0.5*mean(softDTW) + 0.5*sum(E*Omega)/(B*N*N) + MSE
// B=64, N=256, K=1, gamma=0.01.
//
// NEW ALGORITHM (kills the backward recurrence):
//   E[i][j] = exp((Rtot - F[i][j] - B[i][j])/gamma)   (alignment marginal)
//   B[i][j] = G[N+1-i][N+1-j] - D[i][j],  G = same scan on reversed x,t.
// So: scan_kernel with 128 blocks (0-63: F; 64-127: G on reversed inputs),
// all independent -> F and G run CONCURRENTLY on different CUs (wall = one
// scan). Then grad_kernel: pointwise E = exp2((Rtot - F - G' + D)*ESC),
// exponent <= 0 by construction. Scan is the verified R7 (C,S) W=2 code with
// plain compiler stores (asm stores removed: they violated the expcnt
// store-data-register contract -> R9 NaN).
// fma_probe: 16384-deep dependent fma chain; dur_us reveals shader clock
// (~27us @2.4GHz vs ~109us @600MHz).
//
// ws: [0, 128*256*64*16 B = 33.55 MB) F/G column slabs [blk][col][lane];
//     + 1 shared dummy slab (1 KB) + 64*4 doubles partial + probe sink.

#define BB 64
#define NN 256
#define PP 64
#define NPAIR 128
#define NSTEPP 192  // 191 real steps padded to %4
#define NSLAB 256   // real column slabs per block
#define INF_F 100000000.0f
#define ESC 144.26950408889634f   /* (1/gamma) * log2(e) */
#define LSC 0.006931471805599453f /* gamma * ln(2) */

typedef float f32x4 __attribute__((ext_vector_type(4)));

__device__ __forceinline__ float2 cellCS(float2 a, float2 b, float2 c, float t, float x) {
  // softmin in (C,S) form: R = C - LSC*log2(S); chain carries only C.
  const float M = fminf(a.x, fminf(b.x, c.x));
  const float S = a.y * exp2f((M - a.x) * ESC) + b.y * exp2f((M - b.x) * ESC) +
                  c.y * exp2f((M - c.x) * ESC);
  const float d = t - x;
  return make_float2(fmaf(d, d, M), S);
}

__device__ __forceinline__ int clampq(int q) {
  return q < 0 ? 0 : (q > NPAIR - 1 ? NPAIR - 1 : q);
}

#define PAIR_AT(c) make_float2(xs[2 * (c)], xs[2 * (c) + 1])

#define FWD_BODY(S, XQ)                                                        \
  {                                                                            \
    const int q_ = (S)-p;                                                      \
    const bool act_ = (q_ >= 0) & (q_ <= NPAIR - 1);                           \
    const float xa_ = XQ.x, xb_ = XQ.y;                                        \
    const float2 c00 = cellCS(ob, nb0, pcs0, t0, xa_);                         \
    const float2 c01 = cellCS(pcs0, c00, pcs1, t1, xa_);                       \
    const float2 c02 = cellCS(pcs1, c01, pcs2, t2, xa_);                       \
    const float2 c03 = cellCS(pcs2, c02, pcs3, t3, xa_);                       \
    const float2 c10 = cellCS(nb0, nb1, c00, t0, xb_);                         \
    const float2 c11 = cellCS(c00, c10, c01, t1, xb_);                         \
    const float2 c12 = cellCS(c01, c11, c02, t2, xb_);                         \
    const float2 c13 = cellCS(c02, c12, c03, t3, xb_);                         \
    f32x4 st0, st1;                                                            \
    st0.x = fmaf(-LSC, log2f(c00.y), c00.x);                                   \
    st0.y = fmaf(-LSC, log2f(c01.y), c01.x);                                   \
    st0.z = fmaf(-LSC, log2f(c02.y), c02.x);                                   \
    st0.w = fmaf(-LSC, log2f(c03.y), c03.x);                                   \
    st1.x = fmaf(-LSC, log2f(c10.y), c10.x);                                   \
    st1.y = fmaf(-LSC, log2f(c11.y), c11.x);                                   \
    st1.z = fmaf(-LSC, log2f(c12.y), c12.x);                                   \
    st1.w = fmaf(-LSC, log2f(c13.y), c13.x);                                   \
    f32x4* sp0_ = act_ ? (Rb + (size_t)(2 * q_) * PP + p) : (Dum + p);         \
    f32x4* sp1_ = act_ ? (Rb + (size_t)(2 * q_ + 1) * PP + p) : (Dum + p);     \
    *sp0_ = st0;                                                               \
    *sp1_ = st1;                                                               \
    pcs0 = act_ ? c10 : pcs0;                                                  \
    pcs1 = act_ ? c11 : pcs1;                                                  \
    pcs2 = act_ ? c12 : pcs2;                                                  \
    pcs3 = act_ ? c13 : pcs3;                                                  \
    const float eC0_ = act_ ? c03.x : INF_F, eS0_ = act_ ? c03.y : 1.0f;       \
    const float eC1_ = act_ ? c13.x : INF_F, eS1_ = act_ ? c13.y : 1.0f;       \
    const float sC0_ = __shfl_up(eC0_, 1), sS0_ = __shfl_up(eS0_, 1);          \
    const float sC1_ = __shfl_up(eC1_, 1), sS1_ = __shfl_up(eS1_, 1);          \
    ob = nb1;                                                                  \
    nb0 = (p == 0) ? make_float2(INF_F, 1.0f) : make_float2(sC0_, sS0_);       \
    nb1 = (p == 0) ? make_float2(INF_F, 1.0f) : make_float2(sC1_, sS1_);       \
    {                                                                          \
      const int c2_ = clampq((S) + 4 - p);                                     \
      XQ = PAIR_AT(c2_);                                                       \
    }                                                                          \
  }

// blocks 0..63: F-scan on (x,t); blocks 64..127: G-scan on reversed (x,t).
__global__ __launch_bounds__(64, 1) void scan_kernel(
    const float* __restrict__ input, const float* __restrict__ target,
    f32x4* __restrict__ Rws4, f32x4* __restrict__ Dum, double* __restrict__ partial) {
  const int blk = blockIdx.x;
  const int b = blk & (BB - 1);
  const bool rev = blk >= BB;
  const int p = threadIdx.x;
  __shared__ float xs[NN];
  float4 xv = ((const float4*)(input + b * NN))[rev ? (PP - 1 - p) : p];
  float4 tv = ((const float4*)(target + b * NN))[rev ? (PP - 1 - p) : p];
  if (rev) {
    xv = make_float4(xv.w, xv.z, xv.y, xv.x);
    tv = make_float4(tv.w, tv.z, tv.y, tv.x);
  }
  ((float4*)xs)[p] = xv;  // xs = direction-effective x
  const float t0 = tv.x, t1 = tv.y, t2 = tv.z, t3 = tv.w;
  __syncthreads();

  double msel;
  {
    const float d0 = xv.x - tv.x, d1 = xv.y - tv.y;
    const float d2 = xv.z - tv.z, d3 = xv.w - tv.w;
    msel = (double)(d0 * d0) + (double)(d1 * d1) + (double)(d2 * d2) + (double)(d3 * d3);
  }

  f32x4* __restrict__ Rb = Rws4 + (size_t)blk * NSLAB * PP;

  // (C,S) state; boundary R=INF -> (INF,1); R[0][0] = (0,1) on lane 0.
  float2 pcs0 = make_float2(INF_F, 1.0f), pcs1 = pcs0, pcs2 = pcs0, pcs3 = pcs0;
  float2 ob = (p == 0) ? make_float2(0.0f, 1.0f) : make_float2(INF_F, 1.0f);
  float2 nb0 = make_float2(INF_F, 1.0f), nb1 = nb0;
  float2 xq0 = PAIR_AT(clampq(0 - p));
  float2 xq1 = PAIR_AT(clampq(1 - p));
  float2 xq2 = PAIR_AT(clampq(2 - p));
  float2 xq3 = PAIR_AT(clampq(3 - p));

  for (int s = 0; s < NSTEPP; s += 4) {  // 192 steps; s=191 inactive everywhere
    FWD_BODY(s + 0, xq0)
    FWD_BODY(s + 1, xq1)
    FWD_BODY(s + 2, xq2)
    FWD_BODY(s + 3, xq3)
  }
  const float rloc = fmaf(-LSC, log2f(pcs3.y), pcs3.x);  // R[N][N] on lane 63
  const float r_nn = __shfl(rloc, PP - 1);
  for (int off = 32; off > 0; off >>= 1) msel += __shfl_xor(msel, off);
  if (!rev && p == 0) {
    partial[b * 4 + 0] = (double)r_nn;
    partial[b * 4 + 1] = msel;
  }
}

// Pointwise gradient: E[i][j] = exp2((Rtot - F[i][j] - G[i'][j'] + D[i][j])*ESC),
// i' = N+1-i, j' = N+1-j. G float4 at slab 255-jj, lane 63-p, comps reversed.
__global__ __launch_bounds__(256) void grad_kernel(
    const float* __restrict__ input, const float* __restrict__ target,
    const f32x4* __restrict__ Rws4, double* __restrict__ partial) {
  const int b = blockIdx.x;
  const int tid = threadIdx.x;
  const int p = tid & 63;
  const int jg = tid >> 6;
  __shared__ float xsh[NN];
  __shared__ double red[256];
  if (tid < 64) ((float4*)xsh)[tid] = ((const float4*)(input + b * NN))[tid];
  __syncthreads();
  const float4 t4v = ((const float4*)(target + b * NN))[p];  // rows 4p+1..4p+4
  const float Rtot = (float)partial[b * 4 + 0];
  const f32x4* __restrict__ Fb = Rws4 + (size_t)b * NSLAB * PP;
  const f32x4* __restrict__ Gb = Rws4 + (size_t)(b + BB) * NSLAB * PP;
  double ts = 0.0;
  for (int jj = jg; jj < NN; jj += 4) {  // jj = j-1
    const f32x4 F4 = Fb[(size_t)jj * PP + p];
    const f32x4 G4 = Gb[(size_t)(NN - 1 - jj) * PP + (PP - 1 - p)];
    const float xj = xsh[jj];
    const float d0 = t4v.x - xj, d1 = t4v.y - xj, d2 = t4v.z - xj, d3 = t4v.w - xj;
    const float e0 = exp2f((Rtot - F4.x - G4.w + d0 * d0) * ESC);
    const float e1 = exp2f((Rtot - F4.y - G4.z + d1 * d1) * ESC);
    const float e2 = exp2f((Rtot - F4.z - G4.y + d2 * d2) * ESC);
    const float e3 = exp2f((Rtot - F4.w - G4.x + d3 * d3) * ESC);
    const float f0 = (float)(4 * p + 1 - (jj + 1));  // i - j for row k=0
    ts += (double)(e0 * f0 * f0) + (double)(e1 * (f0 + 1) * (f0 + 1)) +
          (double)(e2 * (f0 + 2) * (f0 + 2)) + (double)(e3 * (f0 + 3) * (f0 + 3));
  }
  red[tid] = ts;
  __syncthreads();
  for (int s2 = 128; s2 > 0; s2 >>= 1) {
    if (tid < s2) red[tid] += red[tid + s2];
    __syncthreads();
  }
  if (tid == 0) partial[b * 4 + 2] = red[0];
}

__global__ __launch_bounds__(64) void finalize_kernel(const double* __restrict__ partial,
                                                      float* __restrict__ out) {
  const int t = threadIdx.x;  // one lane per batch
  double sd = partial[t * 4 + 0];
  double ms = partial[t * 4 + 1];
  double ts = partial[t * 4 + 2];
  for (int off = 32; off > 0; off >>= 1) {
    sd += __shfl_xor(sd, off);
    ms += __shfl_xor(ms, off);
    ts += __shfl_xor(ts, off);
  }
  if (t == 0) {
    const double loss_shape = sd / (double)BB;
    const double loss_temporal = ts / ((double)BB * NN * NN);
    const double mse = ms / ((double)BB * NN);
    out[0] = (float)(0.5 * loss_shape + 0.5 * loss_temporal + mse);
  }
}

// Diagnostic: 16384-deep DEPENDENT fma chain; per-link latency is HW-fixed
// (~4 cy), so dur_us measures the shader clock: ~27us @2.4GHz, ~109us @600MHz.
__global__ __launch_bounds__(64, 1) void fma_probe_kernel(const float* __restrict__ in,
                                                          float* __restrict__ sink) {
  float x = in[threadIdx.x];
  const float a = 1.0000001f, c = 1e-7f;
#pragma unroll 16
  for (int i = 0; i < 16384; ++i) x = fmaf(x, a, c);
  sink[threadIdx.x] = x;
}

extern "C" void kernel_launch(void* const* d_in, const int* in_sizes, int n_in,
                              void* d_out, int out_size, void* d_ws, size_t ws_size,
                              hipStream_t stream) {
  const float* input = (const float*)d_in[0];
  const float* target = (const float*)d_in[1];
  f32x4* Rws4 = (f32x4*)d_ws;
  const size_t slabEls = (size_t)2 * BB * NSLAB * PP;  // 128 blocks of slabs
  f32x4* Dum = Rws4 + slabEls;                         // shared dummy slab (64 x 16B)
  double* partial = (double*)(Dum + PP);
  float* sink = (float*)(partial + BB * 4);
  float* out = (float*)d_out;

  scan_kernel<<<2 * BB, PP, 0, stream>>>(input, target, Rws4, Dum, partial);
  grad_kernel<<<BB, 256, 0, stream>>>(input, target, Rws4, partial);
  finalize_kernel<<<1, 64, 0, stream>>>(partial, out);
  fma_probe_kernel<<<1, 64, 0, stream>>>(input, sink);
}

// Round 11
// 234.222 us; speedup vs baseline: 1.5505x; 1.3199x over previous
//
#include <hip/hip_runtime.h>
#include <math.h>

// DILATE loss: 0.5*mean(softDTW) + 0.5*sum(E*Omega)/(B*N*N) + MSE
// B=64, N=256, K=1, gamma=0.01.
//
// Alignment-marginal algorithm (R10, verified): E = exp((Rtot-F-B)/gamma),
// B[i][j] = G[N+1-i][N+1-j] - D[i][j]; F,G from one scan kernel with 128
// independent blocks (0-63: F; 64-127: G on reversed inputs) -> concurrent.
//
// THIS ROUND: issue-bound at true shader clock (R10 probe: ~100us for 65k cy
// -> clock ~0.7-1GHz). So: (1) probe removed; (2) PRE-SCALED domain: inputs
// scaled by sqrt(ESC), scan tracks C' = C*ESC -> all (M-C)*ESC multiplies
// become subs; LSC*ESC == ln2*log2(e) == 1, so stored R' = C' - log2(S) and
// grad exponent is Rtot' - F' - G'' + D' with no scaling ops. ~-14% instr.
// (3) grad 256 blocks (4 chunks/batch).
//
// ws: [0, 33.55 MB) F/G column slabs [blk][col][lane] (f32x4);
//     + dummy slab (1 KB) + 64*6 doubles partial.

#define BB 64
#define NN 256
#define PP 64
#define NPAIR 128
#define NSTEPP 192  // 191 real steps padded to %4
#define NSLAB 256
#define INF_F 100000000.0f
#define SQE 12.01122244f  /* sqrt((1/gamma)*log2(e)) ; ESC = SQE*SQE */

typedef float f32x4 __attribute__((ext_vector_type(4)));

__device__ __forceinline__ float2 cellCS(float2 a, float2 b, float2 c, float t, float x) {
  // scaled-domain softmin: R' = C' - log2(S); no multiplies on the args.
  const float M = fminf(a.x, fminf(b.x, c.x));
  const float S = a.y * exp2f(M - a.x) + b.y * exp2f(M - b.x) + c.y * exp2f(M - c.x);
  const float d = t - x;
  return make_float2(fmaf(d, d, M), S);
}

__device__ __forceinline__ int clampq(int q) {
  return q < 0 ? 0 : (q > NPAIR - 1 ? NPAIR - 1 : q);
}

#define FWD_BODY(S, XQ)                                                        \
  {                                                                            \
    const int q_ = (S)-p;                                                      \
    const bool act_ = (q_ >= 0) & (q_ <= NPAIR - 1);                           \
    const float xa_ = XQ.x, xb_ = XQ.y;                                        \
    const float2 c00 = cellCS(ob, nb0, pcs0, t0, xa_);                         \
    const float2 c01 = cellCS(pcs0, c00, pcs1, t1, xa_);                       \
    const float2 c02 = cellCS(pcs1, c01, pcs2, t2, xa_);                       \
    const float2 c03 = cellCS(pcs2, c02, pcs3, t3, xa_);                       \
    const float2 c10 = cellCS(nb0, nb1, c00, t0, xb_);                         \
    const float2 c11 = cellCS(c00, c10, c01, t1, xb_);                         \
    const float2 c12 = cellCS(c01, c11, c02, t2, xb_);                         \
    const float2 c13 = cellCS(c02, c12, c03, t3, xb_);                         \
    f32x4 st0, st1;                                                            \
    st0.x = c00.x - log2f(c00.y);                                              \
    st0.y = c01.x - log2f(c01.y);                                              \
    st0.z = c02.x - log2f(c02.y);                                              \
    st0.w = c03.x - log2f(c03.y);                                              \
    st1.x = c10.x - log2f(c10.y);                                              \
    st1.y = c11.x - log2f(c11.y);                                              \
    st1.z = c12.x - log2f(c12.y);                                              \
    st1.w = c13.x - log2f(c13.y);                                              \
    f32x4* sp0_ = act_ ? (Rb + (size_t)(2 * q_) * PP + p) : (Dum + p);         \
    f32x4* sp1_ = act_ ? (Rb + (size_t)(2 * q_ + 1) * PP + p) : (Dum + p);     \
    *sp0_ = st0;                                                               \
    *sp1_ = st1;                                                               \
    pcs0 = act_ ? c10 : pcs0;                                                  \
    pcs1 = act_ ? c11 : pcs1;                                                  \
    pcs2 = act_ ? c12 : pcs2;                                                  \
    pcs3 = act_ ? c13 : pcs3;                                                  \
    const float eC0_ = act_ ? c03.x : INF_F, eS0_ = act_ ? c03.y : 1.0f;       \
    const float eC1_ = act_ ? c13.x : INF_F, eS1_ = act_ ? c13.y : 1.0f;       \
    const float sC0_ = __shfl_up(eC0_, 1), sS0_ = __shfl_up(eS0_, 1);          \
    const float sC1_ = __shfl_up(eC1_, 1), sS1_ = __shfl_up(eS1_, 1);          \
    ob = nb1;                                                                  \
    nb0 = (p == 0) ? make_float2(INF_F, 1.0f) : make_float2(sC0_, sS0_);       \
    nb1 = (p == 0) ? make_float2(INF_F, 1.0f) : make_float2(sC1_, sS1_);       \
    XQ = xs2[clampq((S) + 4 - p)];                                             \
  }

// blocks 0..63: F-scan on (x,t); blocks 64..127: G-scan on reversed (x,t).
__global__ __launch_bounds__(64, 1) void scan_kernel(
    const float* __restrict__ input, const float* __restrict__ target,
    f32x4* __restrict__ Rws4, f32x4* __restrict__ Dum, double* __restrict__ partial) {
  const int blk = blockIdx.x;
  const int b = blk & (BB - 1);
  const bool rev = blk >= BB;
  const int p = threadIdx.x;
  __shared__ float2 xs2[NN / 2];
  float4 xv = ((const float4*)(input + b * NN))[rev ? (PP - 1 - p) : p];
  float4 tv = ((const float4*)(target + b * NN))[rev ? (PP - 1 - p) : p];
  if (rev) {
    xv = make_float4(xv.w, xv.z, xv.y, xv.x);
    tv = make_float4(tv.w, tv.z, tv.y, tv.x);
  }
  double msel;
  {
    const float d0 = xv.x - tv.x, d1 = xv.y - tv.y;
    const float d2 = xv.z - tv.z, d3 = xv.w - tv.w;
    msel = (double)(d0 * d0) + (double)(d1 * d1) + (double)(d2 * d2) + (double)(d3 * d3);
  }
  // pre-scale to the R' = R*ESC domain
  xv.x *= SQE; xv.y *= SQE; xv.z *= SQE; xv.w *= SQE;
  tv.x *= SQE; tv.y *= SQE; tv.z *= SQE; tv.w *= SQE;
  ((float4*)xs2)[p] = xv;
  const float t0 = tv.x, t1 = tv.y, t2 = tv.z, t3 = tv.w;
  __syncthreads();

  f32x4* __restrict__ Rb = Rws4 + (size_t)blk * NSLAB * PP;

  float2 pcs0 = make_float2(INF_F, 1.0f), pcs1 = pcs0, pcs2 = pcs0, pcs3 = pcs0;
  float2 ob = (p == 0) ? make_float2(0.0f, 1.0f) : make_float2(INF_F, 1.0f);
  float2 nb0 = make_float2(INF_F, 1.0f), nb1 = nb0;
  float2 xq0 = xs2[clampq(0 - p)];
  float2 xq1 = xs2[clampq(1 - p)];
  float2 xq2 = xs2[clampq(2 - p)];
  float2 xq3 = xs2[clampq(3 - p)];

  for (int s = 0; s < NSTEPP; s += 4) {
    FWD_BODY(s + 0, xq0)
    FWD_BODY(s + 1, xq1)
    FWD_BODY(s + 2, xq2)
    FWD_BODY(s + 3, xq3)
  }
  const float rloc = pcs3.x - log2f(pcs3.y);  // R'[N][N] on lane 63 (scaled)
  const float r_nn = __shfl(rloc, PP - 1);
  for (int off = 32; off > 0; off >>= 1) msel += __shfl_xor(msel, off);
  if (!rev && p == 0) {
    partial[b * 6 + 0] = (double)r_nn;  // scaled; finalize divides by ESC
    partial[b * 6 + 1] = msel;
  }
}

// Pointwise gradient in scaled domain: E = exp2(Rt' - F' - G'' + D'),
// G'' at slab 255-jj, lane 63-p, comps reversed. 4 chunk-blocks per batch.
__global__ __launch_bounds__(256) void grad_kernel(
    const float* __restrict__ input, const float* __restrict__ target,
    const f32x4* __restrict__ Rws4, double* __restrict__ partial) {
  const int b = blockIdx.x >> 2;
  const int ch = blockIdx.x & 3;
  const int tid = threadIdx.x;
  const int p = tid & 63;
  const int jg = tid >> 6;
  __shared__ float xsh[64];
  __shared__ double red[256];
  if (tid < 16) {
    float4 v = ((const float4*)(input + b * NN + ch * 64))[tid];
    v.x *= SQE; v.y *= SQE; v.z *= SQE; v.w *= SQE;
    ((float4*)xsh)[tid] = v;
  }
  __syncthreads();
  float4 tv = ((const float4*)(target + b * NN))[p];  // rows 4p+1..4p+4
  tv.x *= SQE; tv.y *= SQE; tv.z *= SQE; tv.w *= SQE;
  const float Rt = (float)partial[b * 6 + 0];
  const f32x4* __restrict__ Fb = Rws4 + (size_t)b * NSLAB * PP;
  const f32x4* __restrict__ Gb = Rws4 + (size_t)(b + BB) * NSLAB * PP;
  double ts = 0.0;
#pragma unroll 4
  for (int k = 0; k < 16; ++k) {
    const int jl = jg + 4 * k;       // 0..63 within chunk
    const int jj = ch * 64 + jl;     // j-1
    const f32x4 F4 = Fb[(size_t)jj * PP + p];
    const f32x4 G4 = Gb[(size_t)(NN - 1 - jj) * PP + (PP - 1 - p)];
    const float xj = xsh[jl];
    const float d0 = tv.x - xj, d1 = tv.y - xj, d2 = tv.z - xj, d3 = tv.w - xj;
    const float e0 = exp2f(Rt - F4.x - G4.w + d0 * d0);
    const float e1 = exp2f(Rt - F4.y - G4.z + d1 * d1);
    const float e2 = exp2f(Rt - F4.z - G4.y + d2 * d2);
    const float e3 = exp2f(Rt - F4.w - G4.x + d3 * d3);
    const float f0 = (float)(4 * p + 1 - (jj + 1));  // i - j for row k=0
    ts += (double)(e0 * f0 * f0) + (double)(e1 * (f0 + 1) * (f0 + 1)) +
          (double)(e2 * (f0 + 2) * (f0 + 2)) + (double)(e3 * (f0 + 3) * (f0 + 3));
  }
  red[tid] = ts;
  __syncthreads();
  for (int s2 = 128; s2 > 0; s2 >>= 1) {
    if (tid < s2) red[tid] += red[tid + s2];
    __syncthreads();
  }
  if (tid == 0) partial[b * 6 + 2 + ch] = red[0];
}

__global__ __launch_bounds__(64) void finalize_kernel(const double* __restrict__ partial,
                                                      float* __restrict__ out) {
  const int t = threadIdx.x;  // one lane per batch
  const double ESC2 = (double)SQE * (double)SQE;
  double sd = partial[t * 6 + 0] / ESC2;  // un-scale R'_NN
  double ms = partial[t * 6 + 1];
  double ts = partial[t * 6 + 2] + partial[t * 6 + 3] + partial[t * 6 + 4] +
              partial[t * 6 + 5];
  for (int off = 32; off > 0; off >>= 1) {
    sd += __shfl_xor(sd, off);
    ms += __shfl_xor(ms, off);
    ts += __shfl_xor(ts, off);
  }
  if (t == 0) {
    const double loss_shape = sd / (double)BB;
    const double loss_temporal = ts / ((double)BB * NN * NN);
    const double mse = ms / ((double)BB * NN);
    out[0] = (float)(0.5 * loss_shape + 0.5 * loss_temporal + mse);
  }
}

extern "C" void kernel_launch(void* const* d_in, const int* in_sizes, int n_in,
                              void* d_out, int out_size, void* d_ws, size_t ws_size,
                              hipStream_t stream) {
  const float* input = (const float*)d_in[0];
  const float* target = (const float*)d_in[1];
  f32x4* Rws4 = (f32x4*)d_ws;
  const size_t slabEls = (size_t)2 * BB * NSLAB * PP;  // 128 blocks of slabs
  f32x4* Dum = Rws4 + slabEls;                         // shared dummy slab
  double* partial = (double*)(Dum + PP);
  float* out = (float*)d_out;

  scan_kernel<<<2 * BB, PP, 0, stream>>>(input, target, Rws4, Dum, partial);
  grad_kernel<<<4 * BB, 256, 0, stream>>>(input, target, Rws4, partial);
  finalize_kernel<<<1, 64, 0, stream>>>(partial, out);
}

// Round 12
// 166.510 us; speedup vs baseline: 2.1810x; 1.4067x over previous
//
#include <hip/hip_runtime.h>
#include <math.h>

// DILATE loss: 0.5*mean(softDTW) + 0.5*sum(E*Omega)/(B*N*N) + MSE
// B=64, N=256, K=1, gamma=0.01.
//
// Alignment-marginal algorithm (R10/R11, verified): E = exp((Rtot-F-B)/gamma),
// B[i][j] = G[N+1-i][N+1-j] - D[i][j]; F,G from one scan kernel with 128
// independent blocks (0-63: F; 64-127: G on reversed inputs) -> concurrent.
// Scaled domain (R11): inputs pre-multiplied by sqrt(ESC); R' = C' - log2(S).
//
// THIS ROUND: raw-HW transcendentals. exp2f/log2f compile to OCML libcalls
// (~4-6 instr each, range fixups) without fast-math; at 32 calls/step that is
// the dominant issue cost at the measured ~0.9 GHz shader clock. Replace with
// __builtin_amdgcn_exp2f / __builtin_amdgcn_logf (bare v_exp_f32/v_log_f32).
// Safe: exp2 args <= 0 (huge-negative flushes to 0 = wanted); log args in
// [1, 6.5]. Everything else identical to the passing R11 kernel.
//
// ws: [0, 33.55 MB) F/G column slabs [blk][col][lane] (f32x4);
//     + dummy slab (1 KB) + 64*6 doubles partial.

#define BB 64
#define NN 256
#define PP 64
#define NPAIR 128
#define NSTEPP 192  // 191 real steps padded to %4
#define NSLAB 256
#define INF_F 100000000.0f
#define SQE 12.01122244f  /* sqrt((1/gamma)*log2(e)) ; ESC = SQE*SQE */

typedef float f32x4 __attribute__((ext_vector_type(4)));

#define EXP2R(x) __builtin_amdgcn_exp2f(x)  /* raw v_exp_f32 */
#define LOG2R(x) __builtin_amdgcn_logf(x)   /* raw v_log_f32 (log2) */

__device__ __forceinline__ float2 cellCS(float2 a, float2 b, float2 c, float t, float x) {
  // scaled-domain softmin: R' = C' - log2(S); chain: fmin,fmin,sub,exp2,fma.
  const float M = fminf(a.x, fminf(b.x, c.x));
  const float S = a.y * EXP2R(M - a.x) + b.y * EXP2R(M - b.x) + c.y * EXP2R(M - c.x);
  const float d = t - x;
  return make_float2(fmaf(d, d, M), S);
}

__device__ __forceinline__ int clampq(int q) {
  return q < 0 ? 0 : (q > NPAIR - 1 ? NPAIR - 1 : q);
}

#define FWD_BODY(S, XQ)                                                        \
  {                                                                            \
    const int q_ = (S)-p;                                                      \
    const bool act_ = (q_ >= 0) & (q_ <= NPAIR - 1);                           \
    const float xa_ = XQ.x, xb_ = XQ.y;                                        \
    const float2 c00 = cellCS(ob, nb0, pcs0, t0, xa_);                         \
    const float2 c01 = cellCS(pcs0, c00, pcs1, t1, xa_);                       \
    const float2 c02 = cellCS(pcs1, c01, pcs2, t2, xa_);                       \
    const float2 c03 = cellCS(pcs2, c02, pcs3, t3, xa_);                       \
    const float2 c10 = cellCS(nb0, nb1, c00, t0, xb_);                         \
    const float2 c11 = cellCS(c00, c10, c01, t1, xb_);                         \
    const float2 c12 = cellCS(c01, c11, c02, t2, xb_);                         \
    const float2 c13 = cellCS(c02, c12, c03, t3, xb_);                         \
    f32x4 st0, st1;                                                            \
    st0.x = c00.x - LOG2R(c00.y);                                              \
    st0.y = c01.x - LOG2R(c01.y);                                              \
    st0.z = c02.x - LOG2R(c02.y);                                              \
    st0.w = c03.x - LOG2R(c03.y);                                              \
    st1.x = c10.x - LOG2R(c10.y);                                              \
    st1.y = c11.x - LOG2R(c11.y);                                              \
    st1.z = c12.x - LOG2R(c12.y);                                              \
    st1.w = c13.x - LOG2R(c13.y);                                              \
    f32x4* sp0_ = act_ ? (Rb + (size_t)(2 * q_) * PP + p) : (Dum + p);         \
    f32x4* sp1_ = act_ ? (Rb + (size_t)(2 * q_ + 1) * PP + p) : (Dum + p);     \
    *sp0_ = st0;                                                               \
    *sp1_ = st1;                                                               \
    pcs0 = act_ ? c10 : pcs0;                                                  \
    pcs1 = act_ ? c11 : pcs1;                                                  \
    pcs2 = act_ ? c12 : pcs2;                                                  \
    pcs3 = act_ ? c13 : pcs3;                                                  \
    const float eC0_ = act_ ? c03.x : INF_F, eS0_ = act_ ? c03.y : 1.0f;       \
    const float eC1_ = act_ ? c13.x : INF_F, eS1_ = act_ ? c13.y : 1.0f;       \
    const float sC0_ = __shfl_up(eC0_, 1), sS0_ = __shfl_up(eS0_, 1);          \
    const float sC1_ = __shfl_up(eC1_, 1), sS1_ = __shfl_up(eS1_, 1);          \
    ob = nb1;                                                                  \
    nb0 = (p == 0) ? make_float2(INF_F, 1.0f) : make_float2(sC0_, sS0_);       \
    nb1 = (p == 0) ? make_float2(INF_F, 1.0f) : make_float2(sC1_, sS1_);       \
    XQ = xs2[clampq((S) + 4 - p)];                                             \
  }

// blocks 0..63: F-scan on (x,t); blocks 64..127: G-scan on reversed (x,t).
__global__ __launch_bounds__(64, 1) void scan_kernel(
    const float* __restrict__ input, const float* __restrict__ target,
    f32x4* __restrict__ Rws4, f32x4* __restrict__ Dum, double* __restrict__ partial) {
  const int blk = blockIdx.x;
  const int b = blk & (BB - 1);
  const bool rev = blk >= BB;
  const int p = threadIdx.x;
  __shared__ float2 xs2[NN / 2];
  float4 xv = ((const float4*)(input + b * NN))[rev ? (PP - 1 - p) : p];
  float4 tv = ((const float4*)(target + b * NN))[rev ? (PP - 1 - p) : p];
  if (rev) {
    xv = make_float4(xv.w, xv.z, xv.y, xv.x);
    tv = make_float4(tv.w, tv.z, tv.y, tv.x);
  }
  double msel;
  {
    const float d0 = xv.x - tv.x, d1 = xv.y - tv.y;
    const float d2 = xv.z - tv.z, d3 = xv.w - tv.w;
    msel = (double)(d0 * d0) + (double)(d1 * d1) + (double)(d2 * d2) + (double)(d3 * d3);
  }
  // pre-scale to the R' = R*ESC domain
  xv.x *= SQE; xv.y *= SQE; xv.z *= SQE; xv.w *= SQE;
  tv.x *= SQE; tv.y *= SQE; tv.z *= SQE; tv.w *= SQE;
  ((float4*)xs2)[p] = xv;
  const float t0 = tv.x, t1 = tv.y, t2 = tv.z, t3 = tv.w;
  __syncthreads();

  f32x4* __restrict__ Rb = Rws4 + (size_t)blk * NSLAB * PP;

  float2 pcs0 = make_float2(INF_F, 1.0f), pcs1 = pcs0, pcs2 = pcs0, pcs3 = pcs0;
  float2 ob = (p == 0) ? make_float2(0.0f, 1.0f) : make_float2(INF_F, 1.0f);
  float2 nb0 = make_float2(INF_F, 1.0f), nb1 = nb0;
  float2 xq0 = xs2[clampq(0 - p)];
  float2 xq1 = xs2[clampq(1 - p)];
  float2 xq2 = xs2[clampq(2 - p)];
  float2 xq3 = xs2[clampq(3 - p)];

  for (int s = 0; s < NSTEPP; s += 4) {
    FWD_BODY(s + 0, xq0)
    FWD_BODY(s + 1, xq1)
    FWD_BODY(s + 2, xq2)
    FWD_BODY(s + 3, xq3)
  }
  const float rloc = pcs3.x - LOG2R(pcs3.y);  // R'[N][N] on lane 63 (scaled)
  const float r_nn = __shfl(rloc, PP - 1);
  for (int off = 32; off > 0; off >>= 1) msel += __shfl_xor(msel, off);
  if (!rev && p == 0) {
    partial[b * 6 + 0] = (double)r_nn;  // scaled; finalize divides by ESC
    partial[b * 6 + 1] = msel;
  }
}

// Pointwise gradient in scaled domain: E = exp2(Rt' - F' - G'' + D'),
// G'' at slab 255-jj, lane 63-p, comps reversed. 4 chunk-blocks per batch.
__global__ __launch_bounds__(256) void grad_kernel(
    const float* __restrict__ input, const float* __restrict__ target,
    const f32x4* __restrict__ Rws4, double* __restrict__ partial) {
  const int b = blockIdx.x >> 2;
  const int ch = blockIdx.x & 3;
  const int tid = threadIdx.x;
  const int p = tid & 63;
  const int jg = tid >> 6;
  __shared__ float xsh[64];
  __shared__ double red[256];
  if (tid < 16) {
    float4 v = ((const float4*)(input + b * NN + ch * 64))[tid];
    v.x *= SQE; v.y *= SQE; v.z *= SQE; v.w *= SQE;
    ((float4*)xsh)[tid] = v;
  }
  __syncthreads();
  float4 tv = ((const float4*)(target + b * NN))[p];  // rows 4p+1..4p+4
  tv.x *= SQE; tv.y *= SQE; tv.z *= SQE; tv.w *= SQE;
  const float Rt = (float)partial[b * 6 + 0];
  const f32x4* __restrict__ Fb = Rws4 + (size_t)b * NSLAB * PP;
  const f32x4* __restrict__ Gb = Rws4 + (size_t)(b + BB) * NSLAB * PP;
  double ts = 0.0;
#pragma unroll 4
  for (int k = 0; k < 16; ++k) {
    const int jl = jg + 4 * k;       // 0..63 within chunk
    const int jj = ch * 64 + jl;     // j-1
    const f32x4 F4 = Fb[(size_t)jj * PP + p];
    const f32x4 G4 = Gb[(size_t)(NN - 1 - jj) * PP + (PP - 1 - p)];
    const float xj = xsh[jl];
    const float d0 = tv.x - xj, d1 = tv.y - xj, d2 = tv.z - xj, d3 = tv.w - xj;
    const float e0 = EXP2R(Rt - F4.x - G4.w + d0 * d0);
    const float e1 = EXP2R(Rt - F4.y - G4.z + d1 * d1);
    const float e2 = EXP2R(Rt - F4.z - G4.y + d2 * d2);
    const float e3 = EXP2R(Rt - F4.w - G4.x + d3 * d3);
    const float f0 = (float)(4 * p + 1 - (jj + 1));  // i - j for row k=0
    ts += (double)(e0 * f0 * f0) + (double)(e1 * (f0 + 1) * (f0 + 1)) +
          (double)(e2 * (f0 + 2) * (f0 + 2)) + (double)(e3 * (f0 + 3) * (f0 + 3));
  }
  red[tid] = ts;
  __syncthreads();
  for (int s2 = 128; s2 > 0; s2 >>= 1) {
    if (tid < s2) red[tid] += red[tid + s2];
    __syncthreads();
  }
  if (tid == 0) partial[b * 6 + 2 + ch] = red[0];
}

__global__ __launch_bounds__(64) void finalize_kernel(const double* __restrict__ partial,
                                                      float* __restrict__ out) {
  const int t = threadIdx.x;  // one lane per batch
  const double ESC2 = (double)SQE * (double)SQE;
  double sd = partial[t * 6 + 0] / ESC2;  // un-scale R'_NN
  double ms = partial[t * 6 + 1];
  double ts = partial[t * 6 + 2] + partial[t * 6 + 3] + partial[t * 6 + 4] +
              partial[t * 6 + 5];
  for (int off = 32; off > 0; off >>= 1) {
    sd += __shfl_xor(sd, off);
    ms += __shfl_xor(ms, off);
    ts += __shfl_xor(ts, off);
  }
  if (t == 0) {
    const double loss_shape = sd / (double)BB;
    const double loss_temporal = ts / ((double)BB * NN * NN);
    const double mse = ms / ((double)BB * NN);
    out[0] = (float)(0.5 * loss_shape + 0.5 * loss_temporal + mse);
  }
}

extern "C" void kernel_launch(void* const* d_in, const int* in_sizes, int n_in,
                              void* d_out, int out_size, void* d_ws, size_t ws_size,
                              hipStream_t stream) {
  const float* input = (const float*)d_in[0];
  const float* target = (const float*)d_in[1];
  f32x4* Rws4 = (f32x4*)d_ws;
  const size_t slabEls = (size_t)2 * BB * NSLAB * PP;  // 128 blocks of slabs
  f32x4* Dum = Rws4 + slabEls;                         // shared dummy slab
  double* partial = (double*)(Dum + PP);
  float* out = (float*)d_out;

  scan_kernel<<<2 * BB, PP, 0, stream>>>(input, target, Rws4, Dum, partial);
  grad_kernel<<<4 * BB, 256, 0, stream>>>(input, target, Rws4, partial);
  finalize_kernel<<<1, 64, 0, stream>>>(partial, out);
}